// Round 2
// baseline (948.008 us; speedup 1.0000x reference)
//
#include <hip/hip_runtime.h>
#include <hip/hip_bf16.h>

// Problem constants
#define B_   2
#define H_   16
#define SQ_  2048
#define SK_  2048
#define D_   128

// Tiling
#define QT   128   // q rows per block
#define KT   64    // k cols per iteration
#define NITER (SK_/KT)

using bf16x8 = __attribute__((ext_vector_type(8))) __bf16;
using bf16x4 = __attribute__((ext_vector_type(4))) __bf16;
using f32x4  = __attribute__((ext_vector_type(4))) float;

#define MFMA16(a,b,c) __builtin_amdgcn_mfma_f32_16x16x32_bf16(a,b,c,0,0,0)

// LDS pitches in elements (bf16) / bytes (mask)
#define QK_PITCH 136   // Q/K tiles [row][d], 272 B rows (16B-aligned, bank-spread)
#define VT_PITCH 72    // V^T [d][k], 144 B rows
#define P_PITCH  72    // P [q][k], 144 B rows
#define M8_PITCH 72    // mask bytes [q][k], 72 B rows

#define KLDS_BYTES (KT  * QK_PITCH * 2)   // 17408
#define VT_BYTES   (D_  * VT_PITCH * 2)   // 18432
#define P_BYTES    (QT  * P_PITCH  * 2)   // 18432
#define M8_BYTES   (QT  * M8_PITCH)       // 9216
#define SMEM_BYTES (KLDS_BYTES + VT_BYTES + P_BYTES + M8_BYTES)  // 63488 < 64 KiB

__global__ __launch_bounds__(512, 4)
void attn_drop_kernel(const float* __restrict__ Q,
                      const float* __restrict__ K,
                      const float* __restrict__ V,
                      const int*   __restrict__ M,
                      float* __restrict__ Out)
{
    __shared__ __align__(16) char smem[SMEM_BYTES];
    __bf16*  Qs  = (__bf16*)smem;                            // prologue only (overlaps K+V)
    __bf16*  Ks  = (__bf16*)smem;                            // [KT][QK_PITCH]
    __bf16*  Vt  = (__bf16*)(smem + KLDS_BYTES);             // [D_][VT_PITCH]
    __bf16*  Ps  = (__bf16*)(smem + KLDS_BYTES + VT_BYTES);  // [QT][P_PITCH]
    unsigned char* Ms8 = (unsigned char*)(smem + KLDS_BYTES + VT_BYTES + P_BYTES); // [QT][M8_PITCH]

    const int tid  = threadIdx.x;
    const int wave = tid >> 6;   // 0..7, each wave owns 16 q-rows
    const int lane = tid & 63;
    const int quad = lane >> 4;
    const int ln   = lane & 15;

    // XCD-aware bijective swizzle (512 blocks % 8 XCDs == 0):
    // XCD x gets orig ids [64x,64x+64) -> 4 whole heads per XCD, K/V L2-local.
    const int orig = ((blockIdx.x & 7) << 6) | (blockIdx.x >> 3);
    const int bh = orig >> 4;   // head index
    const int qb = orig & 15;   // q-block within head

    const float* qptr = Q + ((size_t)bh*SQ_ + (size_t)qb*QT) * D_;
    const float* kptr = K + (size_t)bh*SK_*D_;
    const float* vptr = V + (size_t)bh*SK_*D_;
    const int*   mptr = M + (size_t)bh*(size_t)SQ_*SK_ + (size_t)qb*QT*SK_;
    float*       optr = Out + ((size_t)bh*SQ_ + (size_t)qb*QT) * D_;

    const int c  = tid & 31;   // float4 column within a 128-wide row
    const int g  = tid >> 5;   // row group 0..15
    const int mc = tid & 15;   // int4 column within a 64-wide mask row
    const int mg = tid >> 4;   // mask row group 0..31

    // ---------------- T14 prefetch registers (tile kt+1 in flight across compute) ----
    // 48 VGPRs total: fits under 128 with qf(16)+Oacc(32)+S(16)+temps.
    float4 kpre[4], vpre[4];
    int4   mpre[4];

    auto load_tile = [&](int kt) {
        const float4* ks = (const float4*)(kptr + (size_t)kt*KT*D_);
        const float4* vs = (const float4*)(vptr + (size_t)kt*KT*D_);
        #pragma unroll
        for (int p = 0; p < 4; ++p) kpre[p] = ks[(g + 16*p)*32 + c];
        #pragma unroll
        for (int i = 0; i < 4; ++i) vpre[i] = vs[(4*g + i)*32 + c];
        const int* mrow = mptr + kt*KT + 4*mc;
        #pragma unroll
        for (int p = 0; p < 4; ++p)
            mpre[p] = *(const int4*)(mrow + (size_t)(mg + 32*p)*SK_);
    };

    auto write_tile = [&]() {
        // K tile [KT][128] -> bf16 LDS row-major
        #pragma unroll
        for (int p = 0; p < 4; ++p) {
            float4 v = kpre[p];
            bf16x4 h = { (__bf16)v.x, (__bf16)v.y, (__bf16)v.z, (__bf16)v.w };
            *(bf16x4*)&Ks[(g + 16*p)*QK_PITCH + 4*c] = h;
        }
        // V^T: thread holds 4 consecutive k rows at fixed d0=4c -> rows of V^T
        const float* ff = (const float*)vpre;
        #pragma unroll
        for (int j = 0; j < 4; ++j) {
            bf16x4 row = { (__bf16)ff[0*4+j], (__bf16)ff[1*4+j],
                           (__bf16)ff[2*4+j], (__bf16)ff[3*4+j] };
            *(bf16x4*)&Vt[(4*c + j)*VT_PITCH + 4*g] = row;  // (d0+j, k=4g..4g+3)
        }
        // mask int4 -> packed bytes (values are 0/1 by construction)
        #pragma unroll
        for (int p = 0; p < 4; ++p) {
            int4 m = mpre[p];
            unsigned pk = (unsigned)(m.x & 1) | ((unsigned)(m.y & 1) << 8)
                        | ((unsigned)(m.z & 1) << 16) | ((unsigned)(m.w & 1) << 24);
            *(unsigned*)&Ms8[(mg + 32*p)*M8_PITCH + 4*mc] = pk;
        }
    };

    // issue tile-0 loads first: latency hides under the whole Q prologue
    load_tile(0);

    // ---------------- Prologue: stage Q tile (128x128 f32 -> bf16 LDS) ----------------
    {
        const float4* src = (const float4*)qptr;   // [128][32] float4
        #pragma unroll
        for (int p = 0; p < 8; ++p) {
            int r = g + 16*p;
            float4 v = src[r*32 + c];
            bf16x4 h = { (__bf16)v.x, (__bf16)v.y, (__bf16)v.z, (__bf16)v.w };
            *(bf16x4*)&Qs[r*QK_PITCH + 4*c] = h;
        }
    }
    __syncthreads();

    // Q fragments register-resident for the whole K loop: wave's 16 q-rows
    bf16x8 qf[4];
    #pragma unroll
    for (int s = 0; s < 4; ++s)
        qf[s] = *(const bf16x8*)&Qs[(16*wave + ln)*QK_PITCH + 32*s + 8*quad];
    // no extra barrier: the loop's first __syncthreads covers the Qs-overwrite hazard

    f32x4 Oacc[8];
    #pragma unroll
    for (int dt = 0; dt < 8; ++dt)
        Oacc[dt] = (f32x4){0.f, 0.f, 0.f, 0.f};

    for (int kt = 0; kt < NITER; ++kt) {
        __syncthreads();        // A: all waves done reading LDS (qf at kt=0, prev tile else)
        write_tile();           // regs(tile kt) -> LDS (vmem already landed during prev compute)
        __syncthreads();        // B: tile kt visible (no outstanding vmem here -> cheap drain)
        if (kt + 1 < NITER) load_tile(kt + 1);   // in flight across the whole compute phase

        // ---- S = Q * K^T  (per wave: 16 q-rows x 64 k-cols)
        f32x4 S[4];
        #pragma unroll
        for (int ct = 0; ct < 4; ++ct)
            S[ct] = (f32x4){0.f, 0.f, 0.f, 0.f};

        __builtin_amdgcn_s_setprio(1);
        #pragma unroll
        for (int s = 0; s < 4; ++s) {
            #pragma unroll
            for (int ct = 0; ct < 4; ++ct) {
                bf16x8 kf = *(const bf16x8*)&Ks[(16*ct + ln)*QK_PITCH + 32*s + 8*quad];
                S[ct] = MFMA16(qf[s], kf, S[ct]);
            }
        }
        __builtin_amdgcn_s_setprio(0);

        // ---- dropout mask from LDS bytes + cast, write P to LDS (per-wave rows)
        #pragma unroll
        for (int ct = 0; ct < 4; ++ct) {
            int row0 = 16*wave + 4*quad;
            int col  = 16*ct + ln;
            #pragma unroll
            for (int r = 0; r < 4; ++r) {
                float pv = Ms8[(row0 + r)*M8_PITCH + col] ? S[ct][r] : 0.0f;
                Ps[(row0 + r)*P_PITCH + col] = (__bf16)pv;   // scale folded into epilogue
            }
        }
        // no barrier needed: each wave reads back only its own P rows (lgkmcnt handles RAW)

        // ---- O += P * V
        __builtin_amdgcn_s_setprio(1);
        #pragma unroll
        for (int ks = 0; ks < 2; ++ks) {
            bf16x8 pf = *(const bf16x8*)&Ps[(16*wave + ln)*P_PITCH + 32*ks + 8*quad];
            #pragma unroll
            for (int dt = 0; dt < 8; ++dt) {
                bf16x8 vf = *(const bf16x8*)&Vt[(16*dt + ln)*VT_PITCH + 32*ks + 8*quad];
                Oacc[dt] = MFMA16(pf, vf, Oacc[dt]);
            }
        }
        __builtin_amdgcn_s_setprio(0);
    }

    // ---- epilogue: apply folded scale 2*sqrt(D) and store fp32
    const float SCALE = 22.62741699796952f;  // 2 * sqrt(128) = 16*sqrt(2)
    #pragma unroll
    for (int dt = 0; dt < 8; ++dt) {
        int row0 = 16*wave + 4*quad;
        #pragma unroll
        for (int r = 0; r < 4; ++r)
            optr[(size_t)(row0 + r)*D_ + 16*dt + ln] = Oacc[dt][r] * SCALE;
    }
}

extern "C" void kernel_launch(void* const* d_in, const int* in_sizes, int n_in,
                              void* d_out, int out_size, void* d_ws, size_t ws_size,
                              hipStream_t stream) {
    (void)in_sizes; (void)n_in; (void)d_ws; (void)ws_size; (void)out_size;
    const float* Q = (const float*)d_in[0];
    const float* K = (const float*)d_in[1];
    const float* V = (const float*)d_in[2];
    const int*   M = (const int*)d_in[3];
    float* Out = (float*)d_out;

    dim3 grid(B_ * H_ * (SQ_ / QT));   // 32 * 16 = 512 blocks
    attn_drop_kernel<<<grid, 512, 0, stream>>>(Q, K, V, M, Out);
}

// Round 4
// 786.697 us; speedup vs baseline: 1.2050x; 1.2050x over previous
//
#include <hip/hip_runtime.h>
#include <hip/hip_bf16.h>

// Problem constants
#define B_   2
#define H_   16
#define SQ_  2048
#define SK_  2048
#define D_   128

// Tiling
#define QT   128   // q rows per block
#define KT   32    // k cols per iteration (small -> prefetch fits in regs, no spill)
#define NITER (SK_/KT)   // 64

using bf16x8 = __attribute__((ext_vector_type(8))) __bf16;
using bf16x4 = __attribute__((ext_vector_type(4))) __bf16;
using bf16x2 = __attribute__((ext_vector_type(2))) __bf16;
using f32x4  = __attribute__((ext_vector_type(4))) float;

#define MFMA16(a,b,c) __builtin_amdgcn_mfma_f32_16x16x32_bf16(a,b,c,0,0,0)

// LDS pitches (bf16 elems / bytes for mask)
#define K_PITCH  136   // K tile rows 272 B: b128 frag reads conflict-free
#define VT_PITCH 40    // V^T rows 80 B (32 data + 8 pad), XOR chunk swizzle
#define P_PITCH  40
#define M8_PITCH 40    // mask bytes

#define KB_   (KT*K_PITCH*2)      // 8704
#define VTB_  (D_*VT_PITCH*2)     // 10240
#define M8B_  (QT*M8_PITCH)       // 5120
#define PSB_  (QT*P_PITCH*2)      // 10240
#define SMEM_BYTES (2*KB_ + 2*VTB_ + 2*M8B_ + PSB_)   // 58368 < 64 KiB

__global__ __launch_bounds__(512, 4)
void attn_drop_kernel(const float* __restrict__ Q,
                      const float* __restrict__ K,
                      const float* __restrict__ V,
                      const int*   __restrict__ M,
                      float* __restrict__ Out)
{
    __shared__ __align__(16) char smem[SMEM_BYTES];
    __bf16* Ps = (__bf16*)(smem + 2*KB_ + 2*VTB_ + 2*M8B_);   // [QT][P_PITCH], wave-local

    const int tid  = threadIdx.x;
    const int wave = tid >> 6;   // 0..7, each wave owns 16 q-rows
    const int lane = tid & 63;
    const int quad = lane >> 4;
    const int ln   = lane & 15;

    // XCD-aware bijective swizzle (512 blocks % 8 XCDs == 0): 4 whole heads per XCD
    const int orig = ((blockIdx.x & 7) << 6) | (blockIdx.x >> 3);
    const int bh = orig >> 4;
    const int qb = orig & 15;

    const float* qptr = Q + ((size_t)bh*SQ_ + (size_t)qb*QT) * D_;
    const float* kptr = K + (size_t)bh*SK_*D_;
    const float* vptr = V + (size_t)bh*SK_*D_;
    const int*   mptr = M + (size_t)bh*(size_t)SQ_*SK_ + (size_t)qb*QT*SK_;
    float*       optr = Out + ((size_t)bh*SQ_ + (size_t)qb*QT) * D_;

    const int c  = tid & 31;   // float4 column within a 128-wide row
    const int g  = tid >> 5;   // row group 0..15
    const int mc = tid & 7;    // int4 column within a 32-wide mask row
    const int mg = tid >> 3;   // mask row group 0..63

    // V^T XOR swizzle constants: physical chunk = logical chunk ^ ((row>>2)&3)
    const int wxor = (2*g) ^ ((c & 3) * 8);              // write: elem offset in row
    const int vrd  = 8 * (quad ^ ((ln >> 2) & 3));       // read: elem offset in row

    // -------- T14 prefetch registers (tile kt+1 in flight across compute): 24 VGPRs
    float4 kpre0, kpre1, vpre0, vpre1;
    int4   mpre0, mpre1;

    auto load_tile = [&](int kt) {
        const float4* ks = (const float4*)(kptr + (size_t)kt*KT*D_);
        const float4* vs = (const float4*)(vptr + (size_t)kt*KT*D_);
        kpre0 = ks[g*32 + c];
        kpre1 = ks[(g+16)*32 + c];
        vpre0 = vs[(2*g  )*32 + c];
        vpre1 = vs[(2*g+1)*32 + c];
        const int* mrow = mptr + kt*KT + 4*mc;
        mpre0 = *(const int4*)(mrow + (size_t)mg*SK_);
        mpre1 = *(const int4*)(mrow + (size_t)(mg+64)*SK_);
    };

    auto write_tile = [&](int b) {
        __bf16* ksb = (__bf16*)(smem + b*KB_);
        __bf16* vtb = (__bf16*)(smem + 2*KB_ + b*VTB_);
        unsigned char* msb = (unsigned char*)(smem + 2*KB_ + 2*VTB_ + b*M8B_);
        // K tile [KT][128] -> row-major bf16 (2-way write, free)
        {
            bf16x4 h0 = { (__bf16)kpre0.x, (__bf16)kpre0.y, (__bf16)kpre0.z, (__bf16)kpre0.w };
            bf16x4 h1 = { (__bf16)kpre1.x, (__bf16)kpre1.y, (__bf16)kpre1.z, (__bf16)kpre1.w };
            *(bf16x4*)&ksb[ g      *K_PITCH + 4*c] = h0;
            *(bf16x4*)&ksb[(g+16)  *K_PITCH + 4*c] = h1;
        }
        // V^T [d][k] with XOR chunk swizzle: thread holds k={2g,2g+1} x d=4c..4c+3
        {
            const float* f0 = (const float*)&vpre0;
            const float* f1 = (const float*)&vpre1;
            #pragma unroll
            for (int j = 0; j < 4; ++j) {
                bf16x2 pr = { (__bf16)f0[j], (__bf16)f1[j] };
                *(bf16x2*)&vtb[(4*c + j)*VT_PITCH + wxor] = pr;
            }
        }
        // mask int4 -> packed bytes
        {
            unsigned pk0 = (unsigned)(mpre0.x & 1) | ((unsigned)(mpre0.y & 1) << 8)
                         | ((unsigned)(mpre0.z & 1) << 16) | ((unsigned)(mpre0.w & 1) << 24);
            unsigned pk1 = (unsigned)(mpre1.x & 1) | ((unsigned)(mpre1.y & 1) << 8)
                         | ((unsigned)(mpre1.z & 1) << 16) | ((unsigned)(mpre1.w & 1) << 24);
            *(unsigned*)&msb[ mg      *M8_PITCH + 4*mc] = pk0;
            *(unsigned*)&msb[(mg+64)  *M8_PITCH + 4*mc] = pk1;
        }
    };

    // prefetch tile 0 first; Q fragments load directly from global (one-time, no LDS)
    load_tile(0);

    bf16x8 qf[4];
    {
        const float* qrow = qptr + (size_t)(16*wave + ln)*D_;
        #pragma unroll
        for (int s = 0; s < 4; ++s) {
            float4 a = *(const float4*)(qrow + 32*s + 8*quad);
            float4 b2 = *(const float4*)(qrow + 32*s + 8*quad + 4);
            qf[s] = (bf16x8){ (__bf16)a.x, (__bf16)a.y, (__bf16)a.z, (__bf16)a.w,
                              (__bf16)b2.x, (__bf16)b2.y, (__bf16)b2.z, (__bf16)b2.w };
        }
    }

    f32x4 Oacc[8];
    #pragma unroll
    for (int dt = 0; dt < 8; ++dt)
        Oacc[dt] = (f32x4){0.f, 0.f, 0.f, 0.f};

    const int row0 = 16*wave + 4*quad;

    for (int kt = 0; kt < NITER; ++kt) {
        const int b = kt & 1;
        write_tile(b);          // regs(tile kt) -> LDS buf b (vmem landed during prev compute)
        __syncthreads();        // buf b visible; buf b^1's last reads were pre-(kt-1)-barrier
        if (kt + 1 < NITER) load_tile(kt + 1);   // in flight across the whole compute phase

        const __bf16* ksb = (const __bf16*)(smem + b*KB_);
        const __bf16* vtb = (const __bf16*)(smem + 2*KB_ + b*VTB_);
        const unsigned char* msb = (const unsigned char*)(smem + 2*KB_ + 2*VTB_ + b*M8B_);

        // ---- S = Q * K^T  (per wave: 16 q-rows x 32 k-cols)
        f32x4 S0 = (f32x4){0.f,0.f,0.f,0.f};
        f32x4 S1 = (f32x4){0.f,0.f,0.f,0.f};
        __builtin_amdgcn_s_setprio(1);
        #pragma unroll
        for (int s = 0; s < 4; ++s) {
            bf16x8 kf0 = *(const bf16x8*)&ksb[ ln      *K_PITCH + 32*s + 8*quad];
            bf16x8 kf1 = *(const bf16x8*)&ksb[(16+ln)  *K_PITCH + 32*s + 8*quad];
            S0 = MFMA16(qf[s], kf0, S0);
            S1 = MFMA16(qf[s], kf1, S1);
        }
        __builtin_amdgcn_s_setprio(0);

        // ---- dropout mask (LDS bytes) + cast, write P (wave-local rows, no barrier)
        #pragma unroll
        for (int r = 0; r < 4; ++r) {
            float p0 = msb[(row0 + r)*M8_PITCH + ln     ] ? S0[r] : 0.0f;
            float p1 = msb[(row0 + r)*M8_PITCH + 16 + ln] ? S1[r] : 0.0f;
            Ps[(row0 + r)*P_PITCH + ln     ] = (__bf16)p0;
            Ps[(row0 + r)*P_PITCH + 16 + ln] = (__bf16)p1;
        }

        // ---- O += P * V
        bf16x8 pf = *(const bf16x8*)&Ps[(16*wave + ln)*P_PITCH + 8*quad];
        __builtin_amdgcn_s_setprio(1);
        #pragma unroll
        for (int dt = 0; dt < 8; ++dt) {
            bf16x8 vf = *(const bf16x8*)&vtb[(16*dt + ln)*VT_PITCH + vrd];
            Oacc[dt] = MFMA16(pf, vf, Oacc[dt]);
        }
        __builtin_amdgcn_s_setprio(0);
    }

    // ---- epilogue: apply folded scale 2*sqrt(D) and store fp32
    const float SCALE = 22.62741699796952f;  // 2 * sqrt(128) = 16*sqrt(2)
    #pragma unroll
    for (int dt = 0; dt < 8; ++dt) {
        #pragma unroll
        for (int r = 0; r < 4; ++r)
            optr[(size_t)(row0 + r)*D_ + 16*dt + ln] = Oacc[dt][r] * SCALE;
    }
}

extern "C" void kernel_launch(void* const* d_in, const int* in_sizes, int n_in,
                              void* d_out, int out_size, void* d_ws, size_t ws_size,
                              hipStream_t stream) {
    (void)in_sizes; (void)n_in; (void)d_ws; (void)ws_size; (void)out_size;
    const float* Q = (const float*)d_in[0];
    const float* K = (const float*)d_in[1];
    const float* V = (const float*)d_in[2];
    const int*   M = (const int*)d_in[3];
    float* Out = (float*)d_out;

    dim3 grid(B_ * H_ * (SQ_ / QT));   // 32 * 16 = 512 blocks
    attn_drop_kernel<<<grid, 512, 0, stream>>>(Q, K, V, M, Out);
}

// Round 5
// 786.111 us; speedup vs baseline: 1.2059x; 1.0007x over previous
//
#include <hip/hip_runtime.h>
#include <hip/hip_bf16.h>

// Problem constants
#define B_   2
#define H_   16
#define SQ_  2048
#define SK_  2048
#define D_   128

// Tiling
#define QT   128
#define KT   32
#define NITER (SK_/KT)   // 64

using bf16x8 = __attribute__((ext_vector_type(8))) __bf16;
using bf16x4 = __attribute__((ext_vector_type(4))) __bf16;
using bf16x2 = __attribute__((ext_vector_type(2))) __bf16;
using f32x4  = __attribute__((ext_vector_type(4))) float;

#define MFMA16(a,b,c) __builtin_amdgcn_mfma_f32_16x16x32_bf16(a,b,c,0,0,0)

// LDS pitches (bf16 elems)
#define K_PITCH  136   // K tile rows 272 B (verified conflict-free b128 frag reads)
#define VT_PITCH 40    // V^T rows 80 B, XOR chunk swizzle (phys chunk = log ^ ((d>>2)&3))

#define KB_   (KT*K_PITCH*2)      // 8704
#define VTB_  (D_*VT_PITCH*2)     // 10240
#define SMEM_BYTES (2*KB_ + 2*VTB_)   // 37888 (mask + P LDS paths eliminated)

__global__ __launch_bounds__(512, 4)
void attn_drop_kernel(const float* __restrict__ Q,
                      const float* __restrict__ K,
                      const float* __restrict__ V,
                      const int*   __restrict__ M,
                      float* __restrict__ Out)
{
    __shared__ __align__(16) char smem[SMEM_BYTES];

    const int tid  = threadIdx.x;
    const int wave = tid >> 6;   // 0..7, each wave owns 16 q-rows
    const int lane = tid & 63;
    const int quad = lane >> 4;
    const int ln   = lane & 15;

    // XCD-aware bijective swizzle (512 % 8 == 0): 4 whole heads per XCD
    const int orig = ((blockIdx.x & 7) << 6) | (blockIdx.x >> 3);
    const int bh = orig >> 4;
    const int qb = orig & 15;

    const float* qptr = Q + ((size_t)bh*SQ_ + (size_t)qb*QT) * D_;
    const float* kptr = K + (size_t)bh*SK_*D_;
    const float* vptr = V + (size_t)bh*SK_*D_;
    const int*   mptr = M + (size_t)bh*(size_t)SQ_*SK_ + (size_t)qb*QT*SK_;
    float*       optr = Out + ((size_t)bh*SQ_ + (size_t)qb*QT) * D_;

    const int c  = tid & 31;   // float4 column within a 128-wide row
    const int g  = tid >> 5;   // row group 0..15

    // V^T write swizzle: elem offset within a d-row for k-pair {2g,2g+1}
    const int wxor = (2*g) ^ ((c & 3) * 8);

    // Mask: each lane loads exactly what it consumes (S^T lane layout: q=ln, k=4quad+r)
    const int* mlane = mptr + (size_t)(16*wave + ln)*SK_ + 4*quad;

    // V-read offsets (swizzle-aware): logical k-chunks (quad>>1) and (quad>>1)|2,
    // physical chunk = logical ^ ((d>>2)&3) = logical ^ ((ln>>2)&3)
    const int x3  = (ln >> 2) & 3;
    const int p0c = (quad >> 1) ^ x3;
    const int vlo = 8*p0c       + 4*(quad & 1);   // k = 4quad..4quad+3
    const int vhi = 8*(p0c ^ 2) + 4*(quad & 1);   // k = 16+4quad..+3

    // -------- prefetch registers (tile kt+1 in flight across compute) --------
    float4 kpre0, kpre1, vpre0, vpre1;
    int4   mpre0, mpre1;

    auto load_kv = [&](int kt) {
        const float4* ks = (const float4*)(kptr + (size_t)kt*KT*D_);
        const float4* vs = (const float4*)(vptr + (size_t)kt*KT*D_);
        kpre0 = ks[g*32 + c];
        kpre1 = ks[(g+16)*32 + c];
        vpre0 = vs[(2*g  )*32 + c];
        vpre1 = vs[(2*g+1)*32 + c];
    };
    auto load_mask = [&](int kt) {
        mpre0 = *(const int4*)(mlane + kt*KT);
        mpre1 = *(const int4*)(mlane + kt*KT + 16);
    };

    auto write_tile = [&](int b) {
        __bf16* ksb = (__bf16*)(smem + b*KB_);
        __bf16* vtb = (__bf16*)(smem + 2*KB_ + b*VTB_);
        // K tile [KT][128] -> row-major bf16
        {
            bf16x4 h0 = { (__bf16)kpre0.x, (__bf16)kpre0.y, (__bf16)kpre0.z, (__bf16)kpre0.w };
            bf16x4 h1 = { (__bf16)kpre1.x, (__bf16)kpre1.y, (__bf16)kpre1.z, (__bf16)kpre1.w };
            *(bf16x4*)&ksb[ g    *K_PITCH + 4*c] = h0;
            *(bf16x4*)&ksb[(g+16)*K_PITCH + 4*c] = h1;
        }
        // V^T [d][k] with XOR chunk swizzle: thread holds k={2g,2g+1} x d=4c..4c+3
        {
            const float* f0 = (const float*)&vpre0;
            const float* f1 = (const float*)&vpre1;
            #pragma unroll
            for (int j = 0; j < 4; ++j) {
                bf16x2 pr = { (__bf16)f0[j], (__bf16)f1[j] };
                *(bf16x2*)&vtb[(4*c + j)*VT_PITCH + wxor] = pr;
            }
        }
    };

    // prologue: prefetch tile 0; Q fragments straight from global (one-time)
    load_kv(0);
    load_mask(0);

    bf16x8 qf[4];
    {
        const float* qrow = qptr + (size_t)(16*wave + ln)*D_;
        #pragma unroll
        for (int s = 0; s < 4; ++s) {
            float4 a  = *(const float4*)(qrow + 32*s + 8*quad);
            float4 b2 = *(const float4*)(qrow + 32*s + 8*quad + 4);
            qf[s] = (bf16x8){ (__bf16)a.x,  (__bf16)a.y,  (__bf16)a.z,  (__bf16)a.w,
                              (__bf16)b2.x, (__bf16)b2.y, (__bf16)b2.z, (__bf16)b2.w };
        }
    }

    f32x4 Oacc[8];
    #pragma unroll
    for (int dt = 0; dt < 8; ++dt)
        Oacc[dt] = (f32x4){0.f, 0.f, 0.f, 0.f};

    const int row0 = 16*wave + 4*quad;

    for (int kt = 0; kt < NITER; ++kt) {
        const int b = kt & 1;
        write_tile(b);          // regs(tile kt) -> LDS buf b
        __syncthreads();        // buf b visible; buf b^1 last read before prev barrier
        if (kt + 1 < NITER) load_kv(kt + 1);   // in flight across whole compute phase

        const __bf16* ksb = (const __bf16*)(smem + b*KB_);
        const __bf16* vtb = (const __bf16*)(smem + 2*KB_ + b*VTB_);

        // ---- S^T = K * Q^T (swapped operands): lane holds q=ln, k=4quad+r (+16ct)
        f32x4 S0 = (f32x4){0.f,0.f,0.f,0.f};
        f32x4 S1 = (f32x4){0.f,0.f,0.f,0.f};
        __builtin_amdgcn_s_setprio(1);
        #pragma unroll
        for (int s = 0; s < 4; ++s) {
            bf16x8 kf0 = *(const bf16x8*)&ksb[ ln    *K_PITCH + 32*s + 8*quad];
            bf16x8 kf1 = *(const bf16x8*)&ksb[(16+ln)*K_PITCH + 32*s + 8*quad];
            S0 = MFMA16(kf0, qf[s], S0);
            S1 = MFMA16(kf1, qf[s], S1);
        }
        __builtin_amdgcn_s_setprio(0);

        // ---- dropout mask from regs -> PV A-fragment (k-permuted, lane-local)
        // A slot j<4: k=4quad+j (ct0); j>=4: k=16+4quad+(j-4) (ct1)
        bf16x8 pa;
        pa[0] = mpre0.x ? (__bf16)S0[0] : (__bf16)0.0f;
        pa[1] = mpre0.y ? (__bf16)S0[1] : (__bf16)0.0f;
        pa[2] = mpre0.z ? (__bf16)S0[2] : (__bf16)0.0f;
        pa[3] = mpre0.w ? (__bf16)S0[3] : (__bf16)0.0f;
        pa[4] = mpre1.x ? (__bf16)S1[0] : (__bf16)0.0f;
        pa[5] = mpre1.y ? (__bf16)S1[1] : (__bf16)0.0f;
        pa[6] = mpre1.z ? (__bf16)S1[2] : (__bf16)0.0f;
        pa[7] = mpre1.w ? (__bf16)S1[3] : (__bf16)0.0f;

        if (kt + 1 < NITER) load_mask(kt + 1);   // after mpre consumed (no clobber)

        // ---- O += P * V : B-fragment built with the SAME k-permutation from V^T LDS
        __builtin_amdgcn_s_setprio(1);
        #pragma unroll
        for (int dt = 0; dt < 8; ++dt) {
            const __bf16* vrow = &vtb[(16*dt + ln)*VT_PITCH];
            bf16x4 va = *(const bf16x4*)&vrow[vlo];   // V[4quad..+3][d]
            bf16x4 vb = *(const bf16x4*)&vrow[vhi];   // V[16+4quad..+3][d]
            bf16x8 vf = { va[0], va[1], va[2], va[3], vb[0], vb[1], vb[2], vb[3] };
            Oacc[dt] = MFMA16(pa, vf, Oacc[dt]);
        }
        __builtin_amdgcn_s_setprio(0);
    }

    // ---- epilogue: apply folded scale 2*sqrt(D) and store fp32
    const float SCALE = 22.62741699796952f;  // 2 * sqrt(128)
    #pragma unroll
    for (int dt = 0; dt < 8; ++dt) {
        #pragma unroll
        for (int r = 0; r < 4; ++r)
            optr[(size_t)(row0 + r)*D_ + 16*dt + ln] = Oacc[dt][r] * SCALE;
    }
}

extern "C" void kernel_launch(void* const* d_in, const int* in_sizes, int n_in,
                              void* d_out, int out_size, void* d_ws, size_t ws_size,
                              hipStream_t stream) {
    (void)in_sizes; (void)n_in; (void)d_ws; (void)ws_size; (void)out_size;
    const float* Q = (const float*)d_in[0];
    const float* K = (const float*)d_in[1];
    const float* V = (const float*)d_in[2];
    const int*   M = (const int*)d_in[3];
    float* Out = (float*)d_out;

    dim3 grid(B_ * H_ * (SQ_ / QT));   // 512 blocks
    attn_drop_kernel<<<grid, 512, 0, stream>>>(Q, K, V, M, Out);
}